// Round 10
// baseline (300.184 us; speedup 1.0000x reference)
//
#include <hip/hip_runtime.h>
#include <hip/hip_bf16.h>

#define N_NODES  10000
#define N_EDGES  64000
#define N_GRAPHS 64
#define HID      64

typedef __attribute__((ext_vector_type(8))) short short8;
typedef __attribute__((ext_vector_type(4))) float f32x4;

__device__ __forceinline__ float lrelu(float v){ return v > 0.f ? v : 0.01f*v; }

__device__ __forceinline__ unsigned short f2bf(float f){
    union { float f; unsigned u; } v; v.f = f;
    unsigned r = v.u + 0x7fff + ((v.u >> 16) & 1);
    return (unsigned short)(r >> 16);
}
__device__ __forceinline__ float bf2f(unsigned short s){
    union { unsigned u; float f; } v; v.u = ((unsigned)s) << 16;
    return v.f;
}
__device__ __forceinline__ short8 pack_bf8(float4 a, float4 b){
    short8 r;
    r[0]=(short)f2bf(a.x); r[1]=(short)f2bf(a.y); r[2]=(short)f2bf(a.z); r[3]=(short)f2bf(a.w);
    r[4]=(short)f2bf(b.x); r[5]=(short)f2bf(b.y); r[6]=(short)f2bf(b.z); r[7]=(short)f2bf(b.w);
    return r;
}

// ---------------- init: zero counts | small weight transposes ----------------
// blocks 0..39: zero counts; 40: nfc_wt; 41/42: w1t; 43/44: b2t
__global__ void __launch_bounds__(256) init_kernel(
        int* __restrict__ counts,
        const float* __restrict__ nfc_w, unsigned short* __restrict__ nfc_wt,
        const float* __restrict__ e1w1, unsigned short* __restrict__ w1t1,
        const float* __restrict__ e2w1, unsigned short* __restrict__ w1t2,
        const float* __restrict__ e1b2, unsigned short* __restrict__ b2t1,
        const float* __restrict__ e2b2, unsigned short* __restrict__ b2t2){
    int b = blockIdx.x, tid = threadIdx.x;
    if (b < 40){
        int i = b * 256 + tid;
        if (i < N_NODES) counts[i] = 0;
    } else if (b == 40){
        // nfc_wt[o*128+i] = bf16(nfc_w[i*64+o])
        for (int idx = tid; idx < 8192; idx += 256){
            int o = idx >> 7, i = idx & 127;
            nfc_wt[idx] = f2bf(nfc_w[i * 64 + o]);
        }
    } else if (b <= 42){
        const float* w1 = (b == 42) ? e2w1 : e1w1;        // [32,64]
        unsigned short* w1t = (b == 42) ? w1t2 : w1t1;    // [64][32]
        for (int idx = tid; idx < 2048; idx += 256){
            int o = idx >> 5, k = idx & 31;
            w1t[idx] = f2bf(w1[k * 64 + o]);
        }
    } else {
        const float* b2 = (b == 44) ? e2b2 : e1b2;        // [64,64] (i,o)
        unsigned short* b2t = (b == 44) ? b2t2 : b2t1;    // [64][64] (o,i)
        for (int idx = tid; idx < 4096; idx += 256){
            int o = idx >> 6, i = idx & 63;
            b2t[idx] = f2bf(b2[i * 64 + o]);
        }
    }
}

// ---------------- pre: nodeFC (MFMA, K=128) | w2conv(x2) | csr_count ----------
#define PRE_NFC 157
#define PRE_W2C 128
#define PRE_CNT 250
__global__ void __launch_bounds__(256) pre_kernel(
        const float* __restrict__ x, const unsigned short* __restrict__ nfc_wt,
        const float* __restrict__ nfc_b, float* __restrict__ hx1,
        const float* __restrict__ e1w2, unsigned short* __restrict__ w2t1,
        const float* __restrict__ e2w2, unsigned short* __restrict__ w2t2,
        const int* __restrict__ src, int* __restrict__ counts){
    __shared__ float tile[64][65];
    int b = blockIdx.x, tid = threadIdx.x;
    int wid = tid >> 6, l = tid & 63;
    int m16 = l & 15, grp = l >> 4;
    if (b < PRE_NFC){
        // hx1[n] = lrelu(x[n] @ nfc_w + nfc_b) via swapped-operand MFMA
        int node = b * 64 + wid * 16 + m16;
        bool ok = node < N_NODES;
        short8 xb[4];
        #pragma unroll
        for (int kq = 0; kq < 4; ++kq){
            if (ok){
                const float* xp = x + (size_t)node * 128 + kq * 32 + grp * 8;
                xb[kq] = pack_bf8(*(const float4*)xp, *(const float4*)(xp + 4));
            } else {
                short8 z = {0,0,0,0,0,0,0,0}; xb[kq] = z;
            }
        }
        #pragma unroll
        for (int TB = 0; TB < 64; TB += 16){
            f32x4 acc = *(const f32x4*)(nfc_b + TB + grp * 4);
            #pragma unroll
            for (int kq = 0; kq < 4; ++kq){
                short8 af = *(const short8*)(nfc_wt + (TB + m16) * 128 + kq * 32 + grp * 8);
                acc = __builtin_amdgcn_mfma_f32_16x16x32_bf16(af, xb[kq], acc, 0, 0, 0);
            }
            f32x4 r;
            r[0] = lrelu(acc[0]); r[1] = lrelu(acc[1]); r[2] = lrelu(acc[2]); r[3] = lrelu(acc[3]);
            if (ok) *(f32x4*)(hx1 + ((size_t)node << 6) + TB + grp * 4) = r;
        }
    } else if (b < PRE_NFC + PRE_W2C){
        int bb = b - PRE_NFC;
        int k = bb & 63;
        const float* srcw = ((bb < 64) ? e1w2 : e2w2) + (size_t)k * 4096;
        unsigned short* dstw = (bb < 64) ? w2t1 : w2t2;
        for (int idx = tid; idx < 4096; idx += 256) tile[idx >> 6][idx & 63] = srcw[idx];
        __syncthreads();
        for (int idx = tid; idx < 4096; idx += 256){
            int o = idx >> 6, i = idx & 63;
            dstw[((size_t)(k * 64 + o) << 6) + i] = f2bf(tile[i][o]);
        }
    } else {
        int e = (b - PRE_NFC - PRE_W2C) * 256 + tid;
        if (e < N_EDGES) atomicAdd(&counts[src[e]], 1);
    }
}

// scan rowptr from counts; also zero the scatter cursor
__global__ void csr_scan_kernel(const int* __restrict__ counts, int* __restrict__ rowptr,
                                int* __restrict__ cursor){
    __shared__ int part[256];
    int tid = threadIdx.x;
    const int CH = (N_NODES + 255) / 256;      // 40
    int base = tid * CH, s = 0;
    for (int i = 0; i < CH; ++i){ int idx = base + i; if (idx < N_NODES){ cursor[idx] = 0; s += counts[idx]; } }
    part[tid] = s; __syncthreads();
    for (int off = 1; off < 256; off <<= 1){
        int v = (tid >= off) ? part[tid - off] : 0;
        __syncthreads();
        part[tid] += v;
        __syncthreads();
    }
    int run = part[tid] - s;
    for (int i = 0; i < CH; ++i){ int idx = base + i; if (idx < N_NODES){ rowptr[idx] = run; run += counts[idx]; } }
    if (tid == 255) rowptr[N_NODES] = run;
}

__global__ void csr_scatter_kernel(const int* __restrict__ src, const int* __restrict__ dst,
                                   const int* __restrict__ rowptr, int* __restrict__ cursor,
                                   int* __restrict__ eidx, int* __restrict__ dsts){
    int e = blockIdx.x * 256 + threadIdx.x;
    if (e >= N_EDGES) return;
    int s = src[e];
    int j = rowptr[s] + atomicAdd(&cursor[s], 1);
    eidx[j] = e; dsts[j] = dst[e];
}

// ---------------- per-layer light kernel (MFMA): t-GEMM | hb2 + agg0 | (hg0) ----------
#define NBT2 1000                  // 64 edges/block
#define NBH2 157                   // 64 nodes/block
template<int L2FLAG>
__global__ void __launch_bounds__(256) layerB_kernel(
        const float* __restrict__ ea, const int* __restrict__ eidx,
        const unsigned short* __restrict__ w1t, const float* __restrict__ b1,
        unsigned short* __restrict__ tp,
        const float* __restrict__ hx, const unsigned short* __restrict__ b2t,
        float* __restrict__ hb2, float* __restrict__ agg, float* __restrict__ hg){
    int b = blockIdx.x, tid = threadIdx.x;
    int wid = tid >> 6, l = tid & 63;
    int m16 = l & 15, grp = l >> 4;

    if (b < NBT2){
        // t[j,out] = bf16(relu(ea[eidx[j]] @ w1 + b1))  via MFMA (K=32), CSR order
        int j = b * 64 + wid * 16 + m16;
        const float* row = ea + (size_t)eidx[j] * 32 + grp * 8;
        short8 ef = pack_bf8(*(const float4*)row, *(const float4*)(row + 4));
        #pragma unroll
        for (int TB = 0; TB < 64; TB += 16){
            short8 wf = *(const short8*)(w1t + (TB + m16) * 32 + grp * 8);
            f32x4 acc = *(const f32x4*)(b1 + TB + grp * 4);
            acc = __builtin_amdgcn_mfma_f32_16x16x32_bf16(wf, ef, acc, 0, 0, 0);
            unsigned p0 = (unsigned)f2bf(fmaxf(acc[0], 0.f)) | ((unsigned)f2bf(fmaxf(acc[1], 0.f)) << 16);
            unsigned p1 = (unsigned)f2bf(fmaxf(acc[2], 0.f)) | ((unsigned)f2bf(fmaxf(acc[3], 0.f)) << 16);
            uint2 pk; pk.x = p0; pk.y = p1;
            *(uint2*)(tp + ((size_t)j << 6) + TB + grp * 4) = pk;
        }
    } else if (b < NBT2 + NBH2){
        // hb2[n,out] = hx[n] @ b2m  via MFMA (K=64); also zero agg rows
        int bb = b - NBT2;
        int node = bb * 64 + wid * 16 + m16;
        short8 h0 = {0,0,0,0,0,0,0,0}, h1 = {0,0,0,0,0,0,0,0};
        if (node < N_NODES){
            const float* hp = hx + ((size_t)node << 6) + grp * 8;
            h0 = pack_bf8(*(const float4*)hp, *(const float4*)(hp + 4));
            h1 = pack_bf8(*(const float4*)(hp + 32), *(const float4*)(hp + 36));
        }
        #pragma unroll
        for (int TB = 0; TB < 64; TB += 16){
            short8 c0 = *(const short8*)(b2t + (TB + m16) * 64 + grp * 8);
            short8 c1 = *(const short8*)(b2t + (TB + m16) * 64 + 32 + grp * 8);
            f32x4 acc = {0.f, 0.f, 0.f, 0.f};
            acc = __builtin_amdgcn_mfma_f32_16x16x32_bf16(c0, h0, acc, 0, 0, 0);
            acc = __builtin_amdgcn_mfma_f32_16x16x32_bf16(c1, h1, acc, 0, 0, 0);
            if (node < N_NODES) *(f32x4*)(hb2 + ((size_t)node << 6) + TB + grp * 4) = acc;
        }
        f32x4 z = {0.f, 0.f, 0.f, 0.f};
        #pragma unroll
        for (int q = 0; q < 4; ++q){
            int chunk = q * 256 + tid;
            int n = bb * 64 + (chunk >> 4), c = (chunk & 15) * 4;
            if (n < N_NODES) *(f32x4*)(agg + ((size_t)n << 6) + c) = z;
        }
    } else if (L2FLAG){
        for (int i = tid; i < N_GRAPHS * 64; i += 256) hg[i] = 0.f;
    }
}

// ---------------- fused gmat+msg: 16 nodes x 2048 cols (k-half) per block ----------------
// G-tile lives only in LDS (64 KB). half = k_out in [half*32, half*32+32).
// Phase 1: swapped-operand MFMA -> stg (XOR swizzle). Phase 2: per-node edge loop,
// gk[32] hoisted to regs; partial msg atomicAdd'ed to agg[dst]; hb2 added by half==0.
__global__ void __launch_bounds__(512) fused_kernel(
        const float* __restrict__ hx, const unsigned short* __restrict__ w2t,
        const unsigned short* __restrict__ tp, const float* __restrict__ hb2,
        const int* __restrict__ rowptr, const int* __restrict__ dsts,
        float* __restrict__ agg){
    __shared__ unsigned short stg[16 * 2048];  // exactly 64 KB
    int tid = threadIdx.x;
    int wid = tid >> 6, l = tid & 63;
    int m16 = l & 15, grp = l >> 4;
    int bx = blockIdx.x >> 1, half = blockIdx.x & 1;
    int n0 = bx * 16;                          // 625*16 = 10000 exact, no bounds checks
    int cb = half * 2048;

    // B fragments: the block's 16 nodes
    const float* hp = hx + ((size_t)(n0 + m16) << 6) + grp * 8;
    short8 b0 = pack_bf8(*(const float4*)hp, *(const float4*)(hp + 4));
    short8 b1 = pack_bf8(*(const float4*)(hp + 32), *(const float4*)(hp + 36));

    // Phase 1: 128 col-tiles over 8 waves (16 each)
    #pragma unroll 4
    for (int tt = 0; tt < 16; ++tt){
        int TB = cb + (wid * 16 + tt) * 16;
        const unsigned short* ap = w2t + ((size_t)(TB + m16) << 6) + grp * 8;
        short8 a0 = *(const short8*)ap;
        short8 a1 = *(const short8*)(ap + 32);
        f32x4 acc = {0.f, 0.f, 0.f, 0.f};
        acc = __builtin_amdgcn_mfma_f32_16x16x32_bf16(a0, b0, acc, 0, 0, 0);
        acc = __builtin_amdgcn_mfma_f32_16x16x32_bf16(a1, b1, acc, 0, 0, 0);
        unsigned p0 = (unsigned)f2bf(acc[0]) | ((unsigned)f2bf(acc[1]) << 16);
        unsigned p1 = (unsigned)f2bf(acc[2]) | ((unsigned)f2bf(acc[3]) << 16);
        int row = m16;                                    // local node
        int colLocal = (TB - cb) + grp * 4;
        int off = (row * 4096 + colLocal * 2) ^ ((row & 7) << 4);
        uint2 pk; pk.x = p0; pk.y = p1;
        *(uint2*)((char*)stg + off) = pk;
    }
    __syncthreads();

    // Phase 2: wave wid handles local nodes wid*2, wid*2+1
    #pragma unroll
    for (int q = 0; q < 2; ++q){
        int ln = wid * 2 + q;
        int s = n0 + ln;
        int r0 = rowptr[s], r1 = rowptr[s + 1];
        if (r0 == r1) continue;
        float gk[32];
        #pragma unroll
        for (int kk = 0; kk < 32; ++kk){
            int off = (ln * 4096 + (kk * 64 + l) * 2) ^ ((ln & 7) << 4);
            gk[kk] = bf2f(*(const unsigned short*)((const char*)stg + off));
        }
        float hb = half ? 0.f : hb2[((size_t)s << 6) + l];
        for (int j = r0; j < r1; ++j){
            const short8* tpe = (const short8*)(tp + ((size_t)j << 6) + half * 32);
            short8 t0 = tpe[0], t1 = tpe[1], t2 = tpe[2], t3 = tpe[3];
            float acc = hb;
            #pragma unroll
            for (int u = 0; u < 8; ++u){
                acc += bf2f((unsigned short)t0[u]) * gk[u];
                acc += bf2f((unsigned short)t1[u]) * gk[8 + u];
                acc += bf2f((unsigned short)t2[u]) * gk[16 + u];
                acc += bf2f((unsigned short)t3[u]) * gk[24 + u];
            }
            atomicAdd(&agg[((size_t)dsts[j] << 6) + l], acc);
        }
    }
}

// out[n,o] = lrelu(agg[n,o] + hx[n] @ root + bias)
__global__ void combine_kernel(const float* __restrict__ agg, const float* __restrict__ hx,
                               const float* __restrict__ root, const float* __restrict__ bias,
                               float* __restrict__ out, int N){
    int m = threadIdx.x;
    int n = blockIdx.x * 4 + threadIdx.y;
    if (n >= N) return;
    float acc = agg[(size_t)n * 64 + m] + bias[m];
    const float* row = hx + (size_t)n * 64;
    #pragma unroll 8
    for (int k = 0; k < 64; ++k) acc += row[k] * root[k * 64 + m];
    out[(size_t)n * 64 + m] = lrelu(acc);
}

// layer-2 combine fused with global_add_pool
__global__ void combine2_kernel(const float* __restrict__ agg, const float* __restrict__ hx,
                                const float* __restrict__ root, const float* __restrict__ bias,
                                const int* __restrict__ batch, float* __restrict__ hg, int N){
    int m = threadIdx.x;
    int n = blockIdx.x * 4 + threadIdx.y;
    if (n >= N) return;
    float acc = agg[(size_t)n * 64 + m] + bias[m];
    const float* row = hx + (size_t)n * 64;
    #pragma unroll 8
    for (int k = 0; k < 64; ++k) acc += row[k] * root[k * 64 + m];
    atomicAdd(&hg[batch[n] * 64 + m], lrelu(acc));
}

__global__ void head_kernel(const float* __restrict__ hg, const float* __restrict__ fc1w,
                            const float* __restrict__ fc1b, const float* __restrict__ fc2w,
                            const float* __restrict__ fc2b, float* __restrict__ out){
    int g = threadIdx.x;                       // 0..63
    const float* row = hg + g * 64;
    float h1[32];
    #pragma unroll
    for (int j = 0; j < 32; ++j){
        float a = fc1b[j];
        #pragma unroll 8
        for (int i = 0; i < 64; ++i) a += row[i] * fc1w[i * 32 + j];
        h1[j] = lrelu(a);
    }
    float o = fc2b[0];
    #pragma unroll
    for (int j = 0; j < 32; ++j) o += h1[j] * fc2w[j];
    out[g] = o;
}

extern "C" void kernel_launch(void* const* d_in, const int* in_sizes, int n_in,
                              void* d_out, int out_size, void* d_ws, size_t ws_size,
                              hipStream_t stream){
    const float* x      = (const float*)d_in[0];
    const int*   ei     = (const int*)  d_in[1];
    const float* ea     = (const float*)d_in[2];
    const int*   batch  = (const int*)  d_in[3];
    const float* nfc_w  = (const float*)d_in[4];
    const float* nfc_b  = (const float*)d_in[5];
    const float* e1w1   = (const float*)d_in[6];
    const float* e1b1   = (const float*)d_in[7];
    const float* e1w2   = (const float*)d_in[8];
    const float* e1b2   = (const float*)d_in[9];
    const float* g1root = (const float*)d_in[10];
    const float* g1bias = (const float*)d_in[11];
    const float* e2w1   = (const float*)d_in[12];
    const float* e2b1   = (const float*)d_in[13];
    const float* e2w2   = (const float*)d_in[14];
    const float* e2b2   = (const float*)d_in[15];
    const float* g2root = (const float*)d_in[16];
    const float* g2bias = (const float*)d_in[17];
    const float* fc1w   = (const float*)d_in[18];
    const float* fc1b   = (const float*)d_in[19];
    const float* fc2w   = (const float*)d_in[20];
    const float* fc2b   = (const float*)d_in[21];
    float* out = (float*)d_out;

    const int* src = ei;
    const int* dst = ei + N_EDGES;

    // workspace carve-up (G buffer eliminated)
    char* ws = (char*)d_ws;
    float* hx1 = (float*)ws;               ws += (size_t)N_NODES * 64 * 4;
    float* hx2 = (float*)ws;               ws += (size_t)N_NODES * 64 * 4;
    unsigned short* tp = (unsigned short*)ws; ws += (size_t)N_EDGES * 64 * 2;  // bf16, CSR order
    float* hb2 = (float*)ws;               ws += (size_t)N_NODES * 64 * 4;
    float* agg = (float*)ws;               ws += (size_t)N_NODES * 64 * 4;
    float* hg  = (float*)ws;               ws += (size_t)N_GRAPHS * 64 * 4;
    unsigned short* w2t1 = (unsigned short*)ws; ws += (size_t)64 * 64 * 64 * 2;
    unsigned short* w2t2 = (unsigned short*)ws; ws += (size_t)64 * 64 * 64 * 2;
    unsigned short* nfc_wt = (unsigned short*)ws; ws += (size_t)8192 * 2;
    unsigned short* w1t1 = (unsigned short*)ws; ws += (size_t)2048 * 2;
    unsigned short* w1t2 = (unsigned short*)ws; ws += (size_t)2048 * 2;
    unsigned short* b2t1 = (unsigned short*)ws; ws += (size_t)4096 * 2;
    unsigned short* b2t2 = (unsigned short*)ws; ws += (size_t)4096 * 2;
    int* counts = (int*)ws;                ws += (size_t)10240 * 4;
    int* cursor = (int*)ws;                ws += (size_t)10240 * 4;
    int* rowptr = (int*)ws;                ws += (size_t)10240 * 4;
    int* eidx   = (int*)ws;                ws += (size_t)N_EDGES * 4;
    int* dsts   = (int*)ws;                ws += (size_t)N_EDGES * 4;

    dim3 blk(64, 4);

    // preamble: init (zero+transposes), pre (nodeFC|w2conv|count), scan, scatter
    init_kernel<<<45, 256, 0, stream>>>(counts, nfc_w, nfc_wt,
                                        e1w1, w1t1, e2w1, w1t2, e1b2, b2t1, e2b2, b2t2);
    pre_kernel<<<PRE_NFC + PRE_W2C + PRE_CNT, 256, 0, stream>>>(
        x, nfc_wt, nfc_b, hx1, e1w2, w2t1, e2w2, w2t2, src, counts);
    csr_scan_kernel<<<1, 256, 0, stream>>>(counts, rowptr, cursor);
    csr_scatter_kernel<<<N_EDGES / 256, 256, 0, stream>>>(src, dst, rowptr, cursor, eidx, dsts);

    // ---------- layer 1 ----------
    layerB_kernel<0><<<NBT2 + NBH2, 256, 0, stream>>>(
        ea, eidx, w1t1, e1b1, tp, hx1, b2t1, hb2, agg, nullptr);
    fused_kernel<<<1250, 512, 0, stream>>>(hx1, w2t1, tp, hb2, rowptr, dsts, agg);
    combine_kernel<<<N_NODES / 4, blk, 0, stream>>>(agg, hx1, g1root, g1bias, hx2, N_NODES);

    // ---------- layer 2 ----------
    layerB_kernel<1><<<NBT2 + NBH2 + 1, 256, 0, stream>>>(
        ea, eidx, w1t2, e2b1, tp, hx2, b2t2, hb2, agg, hg);
    fused_kernel<<<1250, 512, 0, stream>>>(hx2, w2t2, tp, hb2, rowptr, dsts, agg);
    combine2_kernel<<<N_NODES / 4, blk, 0, stream>>>(agg, hx2, g2root, g2bias, batch, hg, N_NODES);

    // head
    head_kernel<<<1, 64, 0, stream>>>(hg, fc1w, fc1b, fc2w, fc2b, out);
}